// Round 1
// baseline (2300.403 us; speedup 1.0000x reference)
//
#include <hip/hip_runtime.h>

#define PTOT   32768
#define KNB    16
#define NCLOUD 16
#define OUTC   512

// ---- order-preserving float<->uint encoding for atomicMax-based float max ----
__device__ __forceinline__ unsigned fenc(float f) {
    unsigned u = __float_as_uint(f);
    return (u & 0x80000000u) ? ~u : (u | 0x80000000u);
}
__device__ __forceinline__ float fdec(unsigned u) {
    unsigned b = (u & 0x80000000u) ? (u & 0x7FFFFFFFu) : ~u;
    return __uint_as_float(b);
}

// ============================ sa1: x1 = max_k relu(diff@W1+b1)@W2 + b2 =======
// block = 8 consecutive points, 128 threads. x1: [P][128] fp32 in ws.
__global__ __launch_bounds__(128) void sa1_kernel(
    const float* __restrict__ pos, const int* __restrict__ nbr,
    const float* __restrict__ W1, const float* __restrict__ b1,
    const float* __restrict__ W2, const float* __restrict__ b2,
    float* __restrict__ x1)
{
    __shared__ float sdiff[KNB][4];
    __shared__ float sht[64][20];      // h transposed: [i][k], row pad 20 floats (80B, 16B-aligned)
    const int tid = threadIdx.x;
    const int i64 = tid & 63;
    // per-thread weight cache (reused across the 8 points)
    const float w1x = W1[i64], w1y = W1[64 + i64], w1z = W1[128 + i64], b1v = b1[i64];
    const float b2v = b2[tid];
    const int p0 = blockIdx.x * 8;

    for (int pi = 0; pi < 8; ++pi) {
        const int p = p0 + pi;
        __syncthreads();   // prev iteration's sht reads done before we rewrite
        if (tid < KNB * 3) {
            int k = tid / 3, d = tid - 3 * k;
            int j = nbr[p * KNB + k];
            sdiff[k][d] = pos[j * 3 + d] - pos[p * 3 + d];
        }
        __syncthreads();
        // layer 1: h[k][i] = relu(b1 + diff.W1col), stored transposed
        {
            const int kbase = tid >> 6;
            #pragma unroll
            for (int g = 0; g < 8; ++g) {
                int k = kbase + 2 * g;
                float v = b1v + sdiff[k][0] * w1x + sdiff[k][1] * w1y + sdiff[k][2] * w1z;
                sht[i64][k] = fmaxf(v, 0.0f);
            }
        }
        __syncthreads();
        // layer 2: thread c=tid: x1[p][c] = max_k sum_i h[k][i]*W2[i][c] + b2[c]
        float acc[KNB];
        #pragma unroll
        for (int k = 0; k < KNB; ++k) acc[k] = 0.0f;
        for (int i = 0; i < 64; ++i) {
            float w = W2[i * 128 + tid];
            float hv[16];
            const float4* hp = (const float4*)&sht[i][0];
            *(float4*)&hv[0]  = hp[0];
            *(float4*)&hv[4]  = hp[1];
            *(float4*)&hv[8]  = hp[2];
            *(float4*)&hv[12] = hp[3];
            #pragma unroll
            for (int k = 0; k < KNB; ++k) acc[k] += hv[k] * w;
        }
        float m = acc[0];
        #pragma unroll
        for (int k = 1; k < KNB; ++k) m = fmaxf(m, acc[k]);
        x1[p * 128 + tid] = m + b2v;
    }
}

// ==== sa2: x2 = max_k relu([x1_j,diff]@W3+b3)@W4 + b4, then per-cloud max ====
// block = 8 consecutive points (2048%8==0 -> same cloud), 256 threads.
__global__ __launch_bounds__(256) void sa2_kernel(
    const float* __restrict__ pos, const int* __restrict__ nbr,
    const int* __restrict__ batch,
    const float* __restrict__ W3, const float* __restrict__ b3,
    const float* __restrict__ W4, const float* __restrict__ b4,
    const float* __restrict__ x1, unsigned* __restrict__ encbuf)
{
    __shared__ float sf[131][20];      // feats transposed: [i][k], pad 20
    __shared__ float sa[256][20];      // relu output transposed: [c][k], pad 20
    __shared__ int   snbr[KNB];
    const int tid = threadIdx.x;
    const float b3v = b3[tid];
    const float b4a = b4[tid], b4b = b4[tid + 256];
    const int p0 = blockIdx.x * 8;
    float rm0 = -3.4e38f, rm1 = -3.4e38f;

    for (int pi = 0; pi < 8; ++pi) {
        const int p = p0 + pi;
        __syncthreads();   // prev iteration's sa reads done
        if (tid < KNB) snbr[tid] = nbr[p * KNB + tid];
        __syncthreads();
        // stage feats_t: rows 0..127 = x1[j], rows 128..130 = pos[j]-pos[p]
        for (int k = 0; k < KNB; ++k) {
            int j = snbr[k];
            if (tid < 131) {
                float v;
                if (tid < 128) v = x1[j * 128 + tid];
                else { int d = tid - 128; v = pos[j * 3 + d] - pos[p * 3 + d]; }
                sf[tid][k] = v;
            }
        }
        __syncthreads();
        // layer 1: thread c=tid: a[c][k] = relu(b3[c] + sum_i feats[k][i]*W3[i][c])
        float acc[KNB];
        #pragma unroll
        for (int k = 0; k < KNB; ++k) acc[k] = b3v;
        for (int i = 0; i < 131; ++i) {
            float w = W3[i * 256 + tid];
            float fv[16];
            const float4* fp = (const float4*)&sf[i][0];
            *(float4*)&fv[0]  = fp[0];
            *(float4*)&fv[4]  = fp[1];
            *(float4*)&fv[8]  = fp[2];
            *(float4*)&fv[12] = fp[3];
            #pragma unroll
            for (int k = 0; k < KNB; ++k) acc[k] += fv[k] * w;
        }
        #pragma unroll
        for (int k = 0; k < KNB; ++k) acc[k] = fmaxf(acc[k], 0.0f);
        {
            float4* ap = (float4*)&sa[tid][0];
            ap[0] = *(float4*)&acc[0];
            ap[1] = *(float4*)&acc[4];
            ap[2] = *(float4*)&acc[8];
            ap[3] = *(float4*)&acc[12];
        }
        __syncthreads();
        // layer 2: thread handles output cols o0=tid, o1=tid+256
        float acc0[KNB], acc1[KNB];
        #pragma unroll
        for (int k = 0; k < KNB; ++k) { acc0[k] = b4a; acc1[k] = b4b; }
        for (int c = 0; c < 256; ++c) {
            float w0 = W4[c * 512 + tid];
            float w1 = W4[c * 512 + 256 + tid];
            float av[16];
            const float4* ap = (const float4*)&sa[c][0];
            *(float4*)&av[0]  = ap[0];
            *(float4*)&av[4]  = ap[1];
            *(float4*)&av[8]  = ap[2];
            *(float4*)&av[12] = ap[3];
            #pragma unroll
            for (int k = 0; k < KNB; ++k) { acc0[k] += av[k] * w0; acc1[k] += av[k] * w1; }
        }
        float m0 = acc0[0], m1 = acc1[0];
        #pragma unroll
        for (int k = 1; k < KNB; ++k) { m0 = fmaxf(m0, acc0[k]); m1 = fmaxf(m1, acc1[k]); }
        rm0 = fmaxf(rm0, m0);
        rm1 = fmaxf(rm1, m1);
    }
    const int b = batch[p0];
    atomicMax(&encbuf[b * OUTC + tid], fenc(rm0));
    atomicMax(&encbuf[b * OUTC + 256 + tid], fenc(rm1));
}

// ============================ finalize: decode encoded maxima ================
__global__ void finalize_kernel(const unsigned* __restrict__ encv,
                                float* __restrict__ out)
{
    int i = blockIdx.x * 256 + threadIdx.x;
    if (i < NCLOUD * OUTC) out[i] = fdec(encv[i]);
}

extern "C" void kernel_launch(void* const* d_in, const int* in_sizes, int n_in,
                              void* d_out, int out_size, void* d_ws, size_t ws_size,
                              hipStream_t stream)
{
    const float* pos   = (const float*)d_in[0];
    const int*   nbr   = (const int*)  d_in[1];
    const int*   batch = (const int*)  d_in[2];
    const float* W1    = (const float*)d_in[3];
    const float* b1    = (const float*)d_in[4];
    const float* W2    = (const float*)d_in[5];
    const float* b2    = (const float*)d_in[6];
    const float* W3    = (const float*)d_in[7];
    const float* b3    = (const float*)d_in[8];
    const float* W4    = (const float*)d_in[9];
    const float* b4    = (const float*)d_in[10];

    float*    x1     = (float*)d_ws;                                     // P*128 fp32 = 16 MB
    unsigned* encbuf = (unsigned*)((char*)d_ws + (size_t)PTOT * 128 * 4); // B*512 uint = 32 KB

    hipMemsetAsync(encbuf, 0, NCLOUD * OUTC * sizeof(unsigned), stream);
    sa1_kernel<<<PTOT / 8, 128, 0, stream>>>(pos, nbr, W1, b1, W2, b2, x1);
    sa2_kernel<<<PTOT / 8, 256, 0, stream>>>(pos, nbr, batch, W3, b3, W4, b4, x1, encbuf);
    finalize_kernel<<<(NCLOUD * OUTC + 255) / 256, 256, 0, stream>>>(encbuf, (float*)d_out);
}

// Round 2
// 418.535 us; speedup vs baseline: 5.4963x; 5.4963x over previous
//
#include <hip/hip_runtime.h>
#include <hip/hip_bf16.h>

#define PTOT   32768
#define KNB    16
#define NCLOUD 16
#define OUTC   512
#define A1S    168   // A1 row stride in ushort (336 B: 16B-aligned, uniform bank spread)
#define A2S    264   // A2 row stride in ushort (528 B: 16B-aligned, words%32==4 -> uniform)

typedef __attribute__((ext_vector_type(8)))  short v8bf;
typedef __attribute__((ext_vector_type(16))) float v16f;

__device__ __forceinline__ unsigned short f2b(float v) {
    __hip_bfloat16 h = __float2bfloat16(v);
    return *reinterpret_cast<unsigned short*>(&h);
}

// ---- order-preserving float<->uint encoding for atomicMax-based float max ----
__device__ __forceinline__ unsigned fenc(float f) {
    unsigned u = __float_as_uint(f);
    return (u & 0x80000000u) ? ~u : (u | 0x80000000u);
}
__device__ __forceinline__ float fdec(unsigned u) {
    unsigned b = (u & 0x80000000u) ? (u & 0x7FFFFFFFu) : ~u;
    return __uint_as_float(b);
}

__device__ __forceinline__ v16f zero16() {
    v16f z;
    #pragma unroll
    for (int i = 0; i < 16; ++i) z[i] = 0.0f;
    return z;
}

// ============ prep: k-major bf16 fragment images of W3 (pad K->160) and W4 ===
// W3s[(c2*256+n)*8+j] = W3[k=c2*8+j][n] (0 if k>=131), c2 in [0,20)
// W4s[(c2*512+n)*8+j] = W4[k=c2*8+j][n],               c2 in [0,32)
__global__ void prep_kernel(const float* __restrict__ W3, const float* __restrict__ W4,
                            unsigned short* __restrict__ W3s, unsigned short* __restrict__ W4s)
{
    int i = blockIdx.x * 256 + threadIdx.x;
    if (i < 40960) {
        int j = i & 7, n = (i >> 3) & 255, c2 = i >> 11;
        int k = c2 * 8 + j;
        W3s[i] = f2b(k < 131 ? W3[k * 256 + n] : 0.0f);
    }
    int i2 = i - 40960;
    if (i2 >= 0 && i2 < 131072) {
        int j = i2 & 7, n = (i2 >> 3) & 511, c2 = i2 >> 12;
        int k = c2 * 8 + j;
        W4s[i2] = f2b(W4[k * 512 + n]);
    }
}

// ============================ sa1: x1 = max_k relu(diff@W1+b1)@W2 + b2 =======
// block = 8 consecutive points, 128 threads. x1b: [P][128] bf16 in ws.
__global__ __launch_bounds__(128) void sa1_kernel(
    const float* __restrict__ pos, const int* __restrict__ nbr,
    const float* __restrict__ W1, const float* __restrict__ b1,
    const float* __restrict__ W2, const float* __restrict__ b2,
    unsigned short* __restrict__ x1b)
{
    __shared__ float sdiff[KNB][4];
    __shared__ float sht[64][20];
    const int tid = threadIdx.x;
    const int i64 = tid & 63;
    const float w1x = W1[i64], w1y = W1[64 + i64], w1z = W1[128 + i64], b1v = b1[i64];
    const float b2v = b2[tid];
    const int p0 = blockIdx.x * 8;

    for (int pi = 0; pi < 8; ++pi) {
        const int p = p0 + pi;
        __syncthreads();
        if (tid < KNB * 3) {
            int k = tid / 3, d = tid - 3 * k;
            int j = nbr[p * KNB + k];
            sdiff[k][d] = pos[j * 3 + d] - pos[p * 3 + d];
        }
        __syncthreads();
        {
            const int kbase = tid >> 6;
            #pragma unroll
            for (int g = 0; g < 8; ++g) {
                int k = kbase + 2 * g;
                float v = b1v + sdiff[k][0] * w1x + sdiff[k][1] * w1y + sdiff[k][2] * w1z;
                sht[i64][k] = fmaxf(v, 0.0f);
            }
        }
        __syncthreads();
        float acc[KNB];
        #pragma unroll
        for (int k = 0; k < KNB; ++k) acc[k] = 0.0f;
        for (int i = 0; i < 64; ++i) {
            float w = W2[i * 128 + tid];
            float hv[16];
            const float4* hp = (const float4*)&sht[i][0];
            *(float4*)&hv[0]  = hp[0];
            *(float4*)&hv[4]  = hp[1];
            *(float4*)&hv[8]  = hp[2];
            *(float4*)&hv[12] = hp[3];
            #pragma unroll
            for (int k = 0; k < KNB; ++k) acc[k] += hv[k] * w;
        }
        float m = acc[0];
        #pragma unroll
        for (int k = 1; k < KNB; ++k) m = fmaxf(m, acc[k]);
        x1b[p * 128 + tid] = f2b(m + b2v);
    }
}

// ==== sa2 (MFMA): per block 4 points (M=64 rows), 256 threads = 4 waves ======
__global__ __launch_bounds__(256, 2) void sa2_kernel(
    const float* __restrict__ pos, const int* __restrict__ nbr,
    const int* __restrict__ batch,
    const unsigned short* __restrict__ W3s, const float* __restrict__ b3,
    const unsigned short* __restrict__ W4s, const float* __restrict__ b4,
    const unsigned short* __restrict__ x1b, unsigned* __restrict__ encbuf)
{
    __shared__ unsigned short A1[64 * A1S];   // 21504 B
    __shared__ unsigned short A2[64 * A2S];   // 33792 B
    const int tid  = threadIdx.x;
    const int lane = tid & 63;
    const int wave = tid >> 6;     // 0..3
    const int l31  = lane & 31;
    const int h    = lane >> 5;    // half-wave
    const int p0   = blockIdx.x * 4;

    // ---- GEMM1 B-fragments (wave owns cols [wave*64, wave*64+64)) — issue early
    v8bf B1[2][10];
    #pragma unroll
    for (int ci = 0; ci < 2; ++ci) {
        int n = (wave * 2 + ci) * 32 + l31;
        #pragma unroll
        for (int kc = 0; kc < 10; ++kc) {
            int c2 = kc * 2 + h;
            B1[ci][kc] = *(const v8bf*)(W3s + ((c2 * 256 + n) << 3));
        }
    }
    float b3v0 = b3[(wave * 2 + 0) * 32 + l31];
    float b3v1 = b3[(wave * 2 + 1) * 32 + l31];

    // ---- stage A1: rows = (point, nbr) pairs; cols 0..127 x1_j, 128..130 diff, ..159 zero
    {
        int r = tid >> 2, q4 = tid & 3;            // 64 rows, 4 threads/row
        int j = nbr[p0 * KNB + r];
        const uint4* src = (const uint4*)(x1b + j * 128 + q4 * 32);
        uint4* dst = (uint4*)(A1 + r * A1S + q4 * 32);
        dst[0] = src[0]; dst[1] = src[1]; dst[2] = src[2]; dst[3] = src[3];
    }
    if (tid < 64) {
        int r = tid;
        int j = nbr[p0 * KNB + r];
        int p = p0 + (r >> 4);
        v8bf z;
        #pragma unroll
        for (int i = 0; i < 8; ++i) z[i] = 0;
        v8bf dv = z;
        dv[0] = (short)f2b(pos[j * 3 + 0] - pos[p * 3 + 0]);
        dv[1] = (short)f2b(pos[j * 3 + 1] - pos[p * 3 + 1]);
        dv[2] = (short)f2b(pos[j * 3 + 2] - pos[p * 3 + 2]);
        *(v8bf*)(A1 + r * A1S + 128) = dv;
        *(v8bf*)(A1 + r * A1S + 136) = z;
        *(v8bf*)(A1 + r * A1S + 144) = z;
        *(v8bf*)(A1 + r * A1S + 152) = z;
    }
    __syncthreads();

    // ---- GEMM1: A2 = bf16(relu(A1 @ W3 + b3)), written in row-major LDS
    #pragma unroll
    for (int ci = 0; ci < 2; ++ci) {
        v16f acc0 = zero16(), acc1 = zero16();
        #pragma unroll
        for (int kc = 0; kc < 10; ++kc) {
            v8bf a0 = *(const v8bf*)(A1 + (l31)      * A1S + kc * 16 + h * 8);
            v8bf a1 = *(const v8bf*)(A1 + (32 + l31) * A1S + kc * 16 + h * 8);
            acc0 = __builtin_amdgcn_mfma_f32_32x32x16_bf16(a0, B1[ci][kc], acc0, 0, 0, 0);
            acc1 = __builtin_amdgcn_mfma_f32_32x32x16_bf16(a1, B1[ci][kc], acc1, 0, 0, 0);
        }
        int c = (wave * 2 + ci) * 32 + l31;
        float bv = ci ? b3v1 : b3v0;
        #pragma unroll
        for (int r = 0; r < 16; ++r) {
            int row = (r & 3) + 8 * (r >> 2) + 4 * h;   // C/D layout row within 32-tile
            A2[row * A2S + c]        = f2b(fmaxf(acc0[r] + bv, 0.0f));
            A2[(32 + row) * A2S + c] = f2b(fmaxf(acc1[r] + bv, 0.0f));
        }
    }

    // ---- GEMM2 B-fragments for first ct-pair: issue before the barrier
    v8bf B2a[16], B2b[16];
    {
        int n0 = (wave * 4) * 32 + l31;
        #pragma unroll
        for (int kc = 0; kc < 16; ++kc) {
            int c2 = kc * 2 + h;
            B2a[kc] = *(const v8bf*)(W4s + ((c2 * 512 + n0) << 3));
            B2b[kc] = *(const v8bf*)(W4s + ((c2 * 512 + n0 + 32) << 3));
        }
    }
    __syncthreads();   // A2 ready

    const int cloud = batch[p0];
    #pragma unroll
    for (int ctp = 0; ctp < 2; ++ctp) {
        if (ctp == 1) {
            int n0 = (wave * 4 + 2) * 32 + l31;
            #pragma unroll
            for (int kc = 0; kc < 16; ++kc) {
                int c2 = kc * 2 + h;
                B2a[kc] = *(const v8bf*)(W4s + ((c2 * 512 + n0) << 3));
                B2b[kc] = *(const v8bf*)(W4s + ((c2 * 512 + n0 + 32) << 3));
            }
        }
        float rm0 = -3.4e38f, rm1 = -3.4e38f;
        #pragma unroll
        for (int rt = 0; rt < 2; ++rt) {
            v16f acc0 = zero16(), acc1 = zero16();
            #pragma unroll
            for (int kc = 0; kc < 16; ++kc) {
                v8bf a = *(const v8bf*)(A2 + (rt * 32 + l31) * A2S + kc * 16 + h * 8);
                acc0 = __builtin_amdgcn_mfma_f32_32x32x16_bf16(a, B2a[kc], acc0, 0, 0, 0);
                acc1 = __builtin_amdgcn_mfma_f32_32x32x16_bf16(a, B2b[kc], acc1, 0, 0, 0);
            }
            float m0 = acc0[0], m1 = acc1[0];
            #pragma unroll
            for (int r = 1; r < 16; ++r) { m0 = fmaxf(m0, acc0[r]); m1 = fmaxf(m1, acc1[r]); }
            rm0 = fmaxf(rm0, m0);
            rm1 = fmaxf(rm1, m1);
        }
        rm0 = fmaxf(rm0, __shfl_xor(rm0, 32));
        rm1 = fmaxf(rm1, __shfl_xor(rm1, 32));
        int ct0 = wave * 4 + ctp * 2;
        rm0 += b4[ct0 * 32 + l31];
        rm1 += b4[(ct0 + 1) * 32 + l31];
        if (lane < 32) {
            atomicMax(&encbuf[cloud * OUTC + ct0 * 32 + l31], fenc(rm0));
            atomicMax(&encbuf[cloud * OUTC + (ct0 + 1) * 32 + l31], fenc(rm1));
        }
    }
}

// ============================ finalize: decode encoded maxima ================
__global__ void finalize_kernel(const unsigned* __restrict__ encv,
                                float* __restrict__ out)
{
    int i = blockIdx.x * 256 + threadIdx.x;
    if (i < NCLOUD * OUTC) out[i] = fdec(encv[i]);
}

extern "C" void kernel_launch(void* const* d_in, const int* in_sizes, int n_in,
                              void* d_out, int out_size, void* d_ws, size_t ws_size,
                              hipStream_t stream)
{
    const float* pos   = (const float*)d_in[0];
    const int*   nbr   = (const int*)  d_in[1];
    const int*   batch = (const int*)  d_in[2];
    const float* W1    = (const float*)d_in[3];
    const float* b1    = (const float*)d_in[4];
    const float* W2    = (const float*)d_in[5];
    const float* b2    = (const float*)d_in[6];
    const float* W3    = (const float*)d_in[7];
    const float* b3    = (const float*)d_in[8];
    const float* W4    = (const float*)d_in[9];
    const float* b4    = (const float*)d_in[10];

    unsigned short* x1b = (unsigned short*)d_ws;                          // 8 MB
    unsigned short* W3s = (unsigned short*)((char*)d_ws + 8388608);       // 80 KB
    unsigned short* W4s = (unsigned short*)((char*)d_ws + 8470528);       // 256 KB
    unsigned*    encbuf = (unsigned*)((char*)d_ws + 8732672);             // 32 KB

    hipMemsetAsync(encbuf, 0, NCLOUD * OUTC * sizeof(unsigned), stream);
    prep_kernel<<<(40960 + 131072 + 255) / 256, 256, 0, stream>>>(W3, W4, W3s, W4s);
    sa1_kernel<<<PTOT / 8, 128, 0, stream>>>(pos, nbr, W1, b1, W2, b2, x1b);
    sa2_kernel<<<PTOT / 4, 256, 0, stream>>>(pos, nbr, batch, W3s, b3, W4s, b4, x1b, encbuf);
    finalize_kernel<<<(NCLOUD * OUTC + 255) / 256, 256, 0, stream>>>(encbuf, (float*)d_out);
}